// Round 1
// baseline (623.512 us; speedup 1.0000x reference)
//
#include <hip/hip_runtime.h>

// Deformable conv fusion, fp32 reference-faithful version.
// Phase A (per block, inline): offset 1x1 conv -> off_lds[72][64]
// Phase B: 72 chunks of (g, k, 32-channel half): bilinear gather -> samp_lds,
//          stage w -> w_lds, 8x8 register-tiled fp32 GEMM accumulate.
// wprep kernel pre-transposes w_def into chunk-contiguous layout in d_ws.

constexpr int H_ = 64, W_ = 256;
constexpr int HWsz = H_ * W_;
constexpr int OC_ = 256;
constexpr int NOFF_ = 72;
constexpr int TP_ = 64;    // pixels per block
constexpr int CCH_ = 32;   // channels per chunk

__global__ __launch_bounds__(256) void wprep_kernel(const float* __restrict__ w_def,
                                                    float* __restrict__ w2) {
    int i = blockIdx.x * 256 + threadIdx.x;     // 72*32*256 = 589824 total
    int oo = i & 255;
    int cc = (i >> 8) & 31;
    int gkh = i >> 13;                          // 0..71
    int half = gkh & 1, gk = gkh >> 1;
    int k = gk % 9, g = gk / 9;
    int cin = g * 64 + half * 32 + cc;
    w2[i] = w_def[(size_t)oo * 2304 + cin * 9 + k];
}

template<bool USE_WS>
__global__ __launch_bounds__(256, 2) void deform_kernel(
    const float* __restrict__ x0, const float* __restrict__ x1,
    const float* __restrict__ x2,
    const float* __restrict__ w_off, const float* __restrict__ b_off,
    const float* __restrict__ w_def, const float* __restrict__ w2,
    float* __restrict__ out)
{
    __shared__ __align__(16) float off_lds[NOFF_][TP_];    // 18 KB
    __shared__ __align__(16) float samp_lds[CCH_][TP_];    // 8 KB
    __shared__ __align__(16) float w_lds[CCH_][OC_];       // 32 KB

    const int tid  = threadIdx.x;
    const int bid  = blockIdx.x;
    const int wt   = bid & 3;          // which 64-px tile of the row
    const int h    = (bid >> 2) & 63;
    const int b    = bid >> 8;
    const int w0   = wt * TP_;
    const int lane = tid & 63;
    const int wv   = tid >> 6;

    // ---- Phase A: offsets for this tile's 64 pixels (72 values each) ----
    {
        const int p  = lane;
        const int o0 = wv * 18;                 // 4 waves x 18 = 72 outputs
        float acc[18];
        #pragma unroll
        for (int j = 0; j < 18; ++j) acc[j] = b_off[o0 + j];
        const int pix = h * W_ + w0 + p;
        const float* s0 = x0 + (size_t)b * 64  * HWsz + pix;
        const float* s1 = x1 + (size_t)b * 64  * HWsz + pix;
        const float* s2 = x2 + (size_t)b * 128 * HWsz + pix;
        for (int c = 0; c < 64; ++c) {
            float xv = s0[(size_t)c * HWsz];
            #pragma unroll
            for (int j = 0; j < 18; ++j) acc[j] += xv * w_off[(o0 + j) * 256 + c];
        }
        for (int c = 0; c < 64; ++c) {
            float xv = s1[(size_t)c * HWsz];
            #pragma unroll
            for (int j = 0; j < 18; ++j) acc[j] += xv * w_off[(o0 + j) * 256 + 64 + c];
        }
        for (int c = 0; c < 128; ++c) {
            float xv = s2[(size_t)c * HWsz];
            #pragma unroll
            for (int j = 0; j < 18; ++j) acc[j] += xv * w_off[(o0 + j) * 256 + 128 + c];
        }
        #pragma unroll
        for (int j = 0; j < 18; ++j) off_lds[o0 + j][p] = acc[j];
    }
    __syncthreads();

    // ---- Phase B: gather + GEMM over 72 chunks ----
    float acc[8][8];
    #pragma unroll
    for (int i = 0; i < 8; ++i)
        #pragma unroll
        for (int j = 0; j < 8; ++j) acc[i][j] = 0.f;

    const int to = tid >> 3;   // 0..31 -> out-channel block o = to*8
    const int tp = tid & 7;    // 0..7  -> pixel block p = tp*8

    for (int gkh = 0; gkh < 72; ++gkh) {
        const int half = gkh & 1, gk = gkh >> 1;
        const int k = gk % 9, g = gk / 9;
        const int ky = k / 3, kx = k % 3;

        // per-lane pixel geometry (redundant across the 4 waves; cheap)
        const int p = lane;
        float dy = off_lds[gk * 2][p];
        float dx = off_lds[gk * 2 + 1][p];
        float py = (float)(h - 1 + ky) + dy;
        float px = (float)(w0 + p - 1 + kx) + dx;
        float y0f = floorf(py), x0f = floorf(px);
        float wy = py - y0f, wx = px - x0f;
        int iy0 = (int)y0f, ix0 = (int)x0f;
        int iy1 = iy0 + 1, ix1 = ix0 + 1;
        float vy0 = (iy0 >= 0 && iy0 < H_) ? 1.f : 0.f;
        float vy1 = (iy1 >= 0 && iy1 < H_) ? 1.f : 0.f;
        float vx0 = (ix0 >= 0 && ix0 < W_) ? 1.f : 0.f;
        float vx1 = (ix1 >= 0 && ix1 < W_) ? 1.f : 0.f;
        float w00 = (1.f - wy) * (1.f - wx) * vy0 * vx0;
        float w01 = (1.f - wy) * wx * vy0 * vx1;
        float w10 = wy * (1.f - wx) * vy1 * vx0;
        float w11 = wy * wx * vy1 * vx1;
        int cy0 = min(max(iy0, 0), H_ - 1), cy1 = min(max(iy1, 0), H_ - 1);
        int cx0 = min(max(ix0, 0), W_ - 1), cx1 = min(max(ix1, 0), W_ - 1);
        int i00 = cy0 * W_ + cx0, i01 = cy0 * W_ + cx1;
        int i10 = cy1 * W_ + cx0, i11 = cy1 * W_ + cx1;

        // deform group -> source array slice (no concat needed)
        const float* src;
        if (g == 0)      src = x0 + (size_t)b * 64  * HWsz;
        else if (g == 1) src = x1 + (size_t)b * 64  * HWsz;
        else if (g == 2) src = x2 + (size_t)b * 128 * HWsz;
        else             src = x2 + (size_t)b * 128 * HWsz + (size_t)64 * HWsz;
        src += (size_t)(half * 32) * HWsz;

        // gather: wave wv covers channels wv*8 .. wv*8+7 of this 32-chunk
        #pragma unroll
        for (int j = 0; j < 8; ++j) {
            const int cc = wv * 8 + j;
            const float* cp = src + (size_t)cc * HWsz;
            float v = w00 * cp[i00] + w01 * cp[i01] + w10 * cp[i10] + w11 * cp[i11];
            samp_lds[cc][p] = v;
        }

        // stage weights for this chunk: w_lds[cc][oo]
        if (USE_WS) {
            const float4* wc = (const float4*)(w2 + (size_t)gkh * (CCH_ * OC_));
            float4* wl = (float4*)(&w_lds[0][0]);
            #pragma unroll
            for (int j = 0; j < 8; ++j) wl[tid + j * 256] = wc[tid + j * 256];
        } else {
            const int cbase = g * 64 + half * 32;
            #pragma unroll
            for (int j = 0; j < 32; ++j)
                w_lds[j][tid] = w_def[(size_t)tid * 2304 + (cbase + j) * 9 + k];
        }

        __syncthreads();

        // 8x8 register-tiled GEMM over the 32-channel chunk
        #pragma unroll 8
        for (int c = 0; c < CCH_; ++c) {
            float4 sa = *(const float4*)&samp_lds[c][tp * 8];
            float4 sb = *(const float4*)&samp_lds[c][tp * 8 + 4];
            float4 wa = *(const float4*)&w_lds[c][to * 8];
            float4 wb = *(const float4*)&w_lds[c][to * 8 + 4];
            float sv[8]  = {sa.x, sa.y, sa.z, sa.w, sb.x, sb.y, sb.z, sb.w};
            float wvv[8] = {wa.x, wa.y, wa.z, wa.w, wb.x, wb.y, wb.z, wb.w};
            #pragma unroll
            for (int i = 0; i < 8; ++i)
                #pragma unroll
                for (int j = 0; j < 8; ++j)
                    acc[i][j] += wvv[i] * sv[j];
        }

        __syncthreads();
    }

    // ---- epilogue: ReLU + store ----
    const size_t obase = (size_t)b * OC_ * HWsz;
    #pragma unroll
    for (int i = 0; i < 8; ++i) {
        int o = to * 8 + i;
        float* orow = out + obase + (size_t)o * HWsz + h * W_ + w0 + tp * 8;
        float4 r0, r1;
        r0.x = fmaxf(acc[i][0], 0.f); r0.y = fmaxf(acc[i][1], 0.f);
        r0.z = fmaxf(acc[i][2], 0.f); r0.w = fmaxf(acc[i][3], 0.f);
        r1.x = fmaxf(acc[i][4], 0.f); r1.y = fmaxf(acc[i][5], 0.f);
        r1.z = fmaxf(acc[i][6], 0.f); r1.w = fmaxf(acc[i][7], 0.f);
        ((float4*)orow)[0] = r0;
        ((float4*)orow)[1] = r1;
    }
}

extern "C" void kernel_launch(void* const* d_in, const int* in_sizes, int n_in,
                              void* d_out, int out_size, void* d_ws, size_t ws_size,
                              hipStream_t stream) {
    const float* x0    = (const float*)d_in[0];
    const float* x1    = (const float*)d_in[1];
    const float* x2    = (const float*)d_in[2];
    const float* w_off = (const float*)d_in[3];
    const float* b_off = (const float*)d_in[4];
    const float* w_def = (const float*)d_in[5];
    float* out = (float*)d_out;
    float* w2  = (float*)d_ws;

    const size_t w2_bytes = (size_t)72 * 32 * 256 * 4;   // 2.36 MB
    if (ws_size >= w2_bytes) {
        hipLaunchKernelGGL(wprep_kernel, dim3(2304), dim3(256), 0, stream, w_def, w2);
        hipLaunchKernelGGL((deform_kernel<true>), dim3(512), dim3(256), 0, stream,
                           x0, x1, x2, w_off, b_off, w_def, w2, out);
    } else {
        hipLaunchKernelGGL((deform_kernel<false>), dim3(512), dim3(256), 0, stream,
                           x0, x1, x2, w_off, b_off, w_def, (const float*)nullptr, out);
    }
}

// Round 2
// 301.306 us; speedup vs baseline: 2.0694x; 2.0694x over previous
//
#include <hip/hip_runtime.h>

// Deformable conv fusion v2: bf16 MFMA main conv.
// - wprep: pack w_def -> d_ws as bf16 in exact 16x16x32 B-fragment order.
// - deform_kernel: Phase A fp32 offset conv (as round 1), Phase B per 32-ch
//   chunk: register-direct A-frag bilinear gather + LDS-staged B-frags
//   (global_load_lds dwordx4, double-buffered, 1 barrier/chunk) + MFMA.

constexpr int H_ = 64, W_ = 256;
constexpr int HWsz = H_ * W_;
constexpr int OC_ = 256;

using f32x4 = __attribute__((ext_vector_type(4))) float;
using s16x8 = __attribute__((ext_vector_type(8))) short;

__device__ __forceinline__ unsigned short f2bf(float f) {
    unsigned u = __float_as_uint(f);
    return (unsigned short)((u + 0x7fffu + ((u >> 16) & 1u)) >> 16);
}

__device__ __forceinline__ void gload_lds16(const void* g, void* l) {
    __builtin_amdgcn_global_load_lds(
        (const __attribute__((address_space(1))) void*)g,
        (__attribute__((address_space(3))) void*)l, 16, 0, 0);
}

// w2 linear bf16 layout: [gkh 72][t 16][lane 64][j 8]
// value = w_def[oc = t*16+(lane&15)][cin = g*64+half*32+(lane>>4)*8+j][k]
__global__ __launch_bounds__(256) void wprep_kernel(const float* __restrict__ w_def,
                                                    unsigned short* __restrict__ w2) {
    int i = blockIdx.x * 256 + threadIdx.x;      // 72*16*64*8 = 589824
    int j = i & 7, lane = (i >> 3) & 63, t = (i >> 9) & 15, gkh = i >> 13;
    int half = gkh & 1, gk = gkh >> 1;
    int k = gk % 9, g = gk / 9;
    int oc = t * 16 + (lane & 15);
    int ch = (lane >> 4) * 8 + j;
    int cin = g * 64 + half * 32 + ch;
    w2[i] = f2bf(w_def[(size_t)oc * 2304 + (size_t)cin * 9 + k]);
}

template<bool USE_WS>
__global__ __launch_bounds__(256, 2) void deform_kernel(
    const float* __restrict__ x0, const float* __restrict__ x1,
    const float* __restrict__ x2,
    const float* __restrict__ w_off, const float* __restrict__ b_off,
    const float* __restrict__ w_def, const unsigned short* __restrict__ w2,
    float* __restrict__ out)
{
    __shared__ __align__(16) float off_lds[72][64];          // 18 KB
    __shared__ __align__(16) unsigned short wbuf[2][8192];   // 2 x 16 KB

    const int tid  = threadIdx.x;
    const int bid  = blockIdx.x;
    const int wt   = bid & 3;
    const int h    = (bid >> 2) & 63;
    const int b    = bid >> 8;
    const int w0   = wt * 64;
    const int lane = tid & 63;
    const int wv   = tid >> 6;

    // ---- w-chunk staging helpers ----
    auto stage_ws = [&](int gkh_n, int bsel) {
        const char* gsrc = (const char*)w2 + (size_t)gkh_n * 16384 + (size_t)tid * 16;
        char* lb = (char*)&wbuf[bsel][0] + wv * 1024;   // wave-uniform base (+lane*16 by HW)
        #pragma unroll
        for (int q = 0; q < 4; ++q)
            gload_lds16(gsrc + q * 4096, lb + q * 4096);
    };
    auto stage_direct = [&](int gkh_n, int bsel) {
        int half = gkh_n & 1, gk = gkh_n >> 1;
        int k = gk % 9, g = gk / 9;
        int cbase = g * 64 + half * 32;
        #pragma unroll
        for (int e = 0; e < 32; ++e) {
            int idx = tid * 32 + e;
            int j = idx & 7, ln = (idx >> 3) & 63, t = idx >> 9;
            int oc = t * 16 + (ln & 15);
            int ch = (ln >> 4) * 8 + j;
            wbuf[bsel][idx] = f2bf(w_def[(size_t)oc * 2304 + (size_t)(cbase + ch) * 9 + k]);
        }
    };

    // prologue: stage chunk 0 (overlaps Phase A)
    if (USE_WS) stage_ws(0, 0); else stage_direct(0, 0);

    // ---- Phase A: offset 1x1 conv (fp32, as round 1) ----
    {
        const int p  = lane;
        const int o0 = wv * 18;
        float acc[18];
        #pragma unroll
        for (int j = 0; j < 18; ++j) acc[j] = b_off[o0 + j];
        const int pix = h * W_ + w0 + p;
        const float* s0 = x0 + (size_t)b * 64  * HWsz + pix;
        const float* s1 = x1 + (size_t)b * 64  * HWsz + pix;
        const float* s2 = x2 + (size_t)b * 128 * HWsz + pix;
        for (int c = 0; c < 64; ++c) {
            float xv = s0[(size_t)c * HWsz];
            #pragma unroll
            for (int j = 0; j < 18; ++j) acc[j] += xv * w_off[(o0 + j) * 256 + c];
        }
        for (int c = 0; c < 64; ++c) {
            float xv = s1[(size_t)c * HWsz];
            #pragma unroll
            for (int j = 0; j < 18; ++j) acc[j] += xv * w_off[(o0 + j) * 256 + 64 + c];
        }
        for (int c = 0; c < 128; ++c) {
            float xv = s2[(size_t)c * HWsz];
            #pragma unroll
            for (int j = 0; j < 18; ++j) acc[j] += xv * w_off[(o0 + j) * 256 + 128 + c];
        }
        #pragma unroll
        for (int j = 0; j < 18; ++j) off_lds[o0 + j][p] = acc[j];
    }
    __syncthreads();

    // ---- Phase B: MFMA main loop ----
    f32x4 acc[16];
    {
        f32x4 z = {0.f, 0.f, 0.f, 0.f};
        #pragma unroll
        for (int t = 0; t < 16; ++t) acc[t] = z;
    }

    const int p  = wv * 16 + (lane & 15);    // this lane's pixel (A-frag row)
    const int cq = lane >> 4;                // channel quad (A-frag k-group)
    const size_t bx64  = (size_t)b * 64  * HWsz;
    const size_t bx128 = (size_t)b * 128 * HWsz;

    for (int gkh = 0; gkh < 72; ++gkh) {
        const int cur = gkh & 1;
        const int half = gkh & 1, gk = gkh >> 1;
        const int k = gk % 9, g = gk / 9;
        const int ky = k / 3, kx = k % 3;

        // geometry (once per chunk per lane)
        float dy = off_lds[gk * 2][p];
        float dx = off_lds[gk * 2 + 1][p];
        float fy = (float)(h - 1 + ky) + dy;
        float fx = (float)(w0 + p - 1 + kx) + dx;
        float y0f = floorf(fy), x0f = floorf(fx);
        float wy = fy - y0f, wx = fx - x0f;
        int iy0 = (int)y0f, ix0 = (int)x0f;
        int iy1 = iy0 + 1, ix1 = ix0 + 1;
        float vy0 = (iy0 >= 0 && iy0 < H_) ? 1.f : 0.f;
        float vy1 = (iy1 >= 0 && iy1 < H_) ? 1.f : 0.f;
        float vx0 = (ix0 >= 0 && ix0 < W_) ? 1.f : 0.f;
        float vx1 = (ix1 >= 0 && ix1 < W_) ? 1.f : 0.f;
        float w00 = (1.f - wy) * (1.f - wx) * vy0 * vx0;
        float w01 = (1.f - wy) * wx * vy0 * vx1;
        float w10 = wy * (1.f - wx) * vy1 * vx0;
        float w11 = wy * wx * vy1 * vx1;
        int cy0 = min(max(iy0, 0), H_ - 1), cy1 = min(max(iy1, 0), H_ - 1);
        int cx0 = min(max(ix0, 0), W_ - 1), cx1 = min(max(ix1, 0), W_ - 1);
        int i00 = cy0 * W_ + cx0, i01 = cy0 * W_ + cx1;
        int i10 = cy1 * W_ + cx0, i11 = cy1 * W_ + cx1;

        const float* src;
        if (g == 0)      src = x0 + bx64;
        else if (g == 1) src = x1 + bx64;
        else if (g == 2) src = x2 + bx128;
        else             src = x2 + bx128 + (size_t)64 * HWsz;
        src += (size_t)(half * 32 + cq * 8) * HWsz;

        // register-direct A-frag gather: 8 channels for this lane's pixel
        float v[8];
        #pragma unroll
        for (int j = 0; j < 8; ++j) {
            const float* cp = src + (size_t)j * HWsz;
            v[j] = fmaf(w00, cp[i00], fmaf(w01, cp[i01], fmaf(w10, cp[i10], w11 * cp[i11])));
        }

        __syncthreads();   // buf[cur] staged (vmcnt drain) + prev reads of buf[cur^1] done

        if (gkh < 71) { if (USE_WS) stage_ws(gkh + 1, cur ^ 1); else stage_direct(gkh + 1, cur ^ 1); }

        s16x8 a;
        #pragma unroll
        for (int j = 0; j < 8; ++j) a[j] = (short)f2bf(v[j]);

        const unsigned short* bufc = &wbuf[cur][0];
        #pragma unroll
        for (int t = 0; t < 16; ++t) {
            s16x8 bf = *(const s16x8*)(bufc + t * 512 + lane * 8);  // ds_read_b128
            acc[t] = __builtin_amdgcn_mfma_f32_16x16x32_bf16(a, bf, acc[t], 0, 0, 0);
        }
    }

    // ---- epilogue: ReLU + float4 stores ----
    // D layout: row(px) = cq*4+i (+wv*16), col(oc) = t*16 + (lane&15)
    const size_t obase = (size_t)b * OC_ * HWsz + (size_t)h * W_ + w0 + wv * 16 + cq * 4;
    #pragma unroll
    for (int t = 0; t < 16; ++t) {
        int oc = t * 16 + (lane & 15);
        float4 r;
        r.x = fmaxf(acc[t][0], 0.f);
        r.y = fmaxf(acc[t][1], 0.f);
        r.z = fmaxf(acc[t][2], 0.f);
        r.w = fmaxf(acc[t][3], 0.f);
        *(float4*)(out + obase + (size_t)oc * HWsz) = r;
    }
}

extern "C" void kernel_launch(void* const* d_in, const int* in_sizes, int n_in,
                              void* d_out, int out_size, void* d_ws, size_t ws_size,
                              hipStream_t stream) {
    const float* x0    = (const float*)d_in[0];
    const float* x1    = (const float*)d_in[1];
    const float* x2    = (const float*)d_in[2];
    const float* w_off = (const float*)d_in[3];
    const float* b_off = (const float*)d_in[4];
    const float* w_def = (const float*)d_in[5];
    float* out = (float*)d_out;
    unsigned short* w2 = (unsigned short*)d_ws;

    const size_t w2_bytes = (size_t)72 * 16 * 64 * 8 * 2;   // 1.18 MB
    if (ws_size >= w2_bytes) {
        hipLaunchKernelGGL(wprep_kernel, dim3(2304), dim3(256), 0, stream, w_def, w2);
        hipLaunchKernelGGL((deform_kernel<true>), dim3(512), dim3(256), 0, stream,
                           x0, x1, x2, w_off, b_off, w_def, w2, out);
    } else {
        hipLaunchKernelGGL((deform_kernel<false>), dim3(512), dim3(256), 0, stream,
                           x0, x1, x2, w_off, b_off, w_def, (const unsigned short*)nullptr, out);
    }
}